// Round 1
// baseline (132.557 us; speedup 1.0000x reference)
//
#include <hip/hip_runtime.h>

#define BSZ 4096
#define D 1024
#define N2 8192
#define TEMPV 0.5f
// exp(x/T) = exp2(x * log2(e)/T)
#define EXPSCALE 2.8853900817779268f

typedef __attribute__((ext_vector_type(8))) short bf16x8;
typedef __attribute__((ext_vector_type(4))) float f32x4;

__device__ inline unsigned short f2bf(float x) {
  unsigned int u = __float_as_uint(x);
  u += 0x7fffu + ((u >> 16) & 1u);   // round-to-nearest-even
  return (unsigned short)(u >> 16);
}

__device__ inline void gload16(const void* g, void* l) {
  __builtin_amdgcn_global_load_lds(
      (const __attribute__((address_space(1))) void*)g,
      (__attribute__((address_space(3))) void*)l, 16, 0, 0);
}

// ---------------- Kernel A: L2-normalize rows, emit bf16 reps + pos dot ----------------
__global__ __launch_bounds__(256) void knorm(const float* __restrict__ ei,
                                             const float* __restrict__ ej,
                                             unsigned short* __restrict__ reps,
                                             float* __restrict__ pos) {
  const int r = blockIdx.x;
  const int t = threadIdx.x;
  const float4 vi = ((const float4*)(ei + (size_t)r * D))[t];
  const float4 vj = ((const float4*)(ej + (size_t)r * D))[t];
  float ssi = vi.x * vi.x + vi.y * vi.y + vi.z * vi.z + vi.w * vi.w;
  float ssj = vj.x * vj.x + vj.y * vj.y + vj.z * vj.z + vj.w * vj.w;
  float sij = vi.x * vj.x + vi.y * vj.y + vi.z * vj.z + vi.w * vj.w;
#pragma unroll
  for (int o = 32; o > 0; o >>= 1) {
    ssi += __shfl_xor(ssi, o);
    ssj += __shfl_xor(ssj, o);
    sij += __shfl_xor(sij, o);
  }
  __shared__ float red[12];
  const int lane = t & 63, wid = t >> 6;
  if (lane == 0) { red[wid * 3] = ssi; red[wid * 3 + 1] = ssj; red[wid * 3 + 2] = sij; }
  __syncthreads();
  ssi = red[0] + red[3] + red[6] + red[9];
  ssj = red[1] + red[4] + red[7] + red[10];
  sij = red[2] + red[5] + red[8] + red[11];
  const float inv_i = rsqrtf(fmaxf(ssi, 1e-24f));
  const float inv_j = rsqrtf(fmaxf(ssj, 1e-24f));
  ushort4 ui, uj;
  ui.x = f2bf(vi.x * inv_i); ui.y = f2bf(vi.y * inv_i);
  ui.z = f2bf(vi.z * inv_i); ui.w = f2bf(vi.w * inv_i);
  uj.x = f2bf(vj.x * inv_j); uj.y = f2bf(vj.y * inv_j);
  uj.z = f2bf(vj.z * inv_j); uj.w = f2bf(vj.w * inv_j);
  *((ushort4*)(reps + (size_t)r * D) + t) = ui;
  *((ushort4*)(reps + (size_t)(BSZ + r) * D) + t) = uj;
  if (t == 0) pos[r] = sij * inv_i * inv_j;
}

// ---------------- Kernel B: upper-triangle 128x128 bf16 MFMA GEMM + exp + row/col sums ----
__global__ __launch_bounds__(256) void kgemm(const short* __restrict__ reps,
                                             float* __restrict__ partial) {
  // map linear bid -> (rb, cb) with cb >= rb (upper triangle incl. diagonal)
  int rem = blockIdx.x;
  int rb = 0;
  while (rem >= 64 - rb) { rem -= 64 - rb; rb++; }
  const int cb = rb + rem;

  __shared__ short lA[128 * 64];
  __shared__ short lB[128 * 64];

  const int t = threadIdx.x;
  const int l = t & 63, w = t >> 6;
  const int wr = w >> 1, wc = w & 1;
  const int r0 = wr * 64, c0 = wc * 64;

  f32x4 acc[4][4];
  const f32x4 zero4 = {0.f, 0.f, 0.f, 0.f};
#pragma unroll
  for (int m = 0; m < 4; m++)
#pragma unroll
    for (int n = 0; n < 4; n++) acc[m][n] = zero4;

  const int srow = w * 32 + (l >> 3);          // staging row (add i*8)
  const int scol = ((l & 7) ^ (l >> 3)) * 8;   // pre-swizzled source col (elements)
  const int ar0 = rb * 128, br0 = cb * 128;

  for (int kt = 0; kt < 16; ++kt) {
    const int k0 = kt * 64;
#pragma unroll
    for (int i = 0; i < 4; i++) {
      const int rl = srow + i * 8;
      gload16(reps + (size_t)(ar0 + rl) * D + k0 + scol, &lA[(w * 32 + i * 8) * 64]);
      gload16(reps + (size_t)(br0 + rl) * D + k0 + scol, &lB[(w * 32 + i * 8) * 64]);
    }
    __syncthreads();
#pragma unroll
    for (int kk = 0; kk < 2; kk++) {
      bf16x8 af[4], bfr[4];
      const int kbyte = kk * 64 + (l >> 4) * 16;
#pragma unroll
      for (int m = 0; m < 4; m++) {
        const int row = r0 + m * 16 + (l & 15);
        af[m] = *(const bf16x8*)((const char*)lA + row * 128 + (kbyte ^ ((row & 7) << 4)));
      }
#pragma unroll
      for (int n = 0; n < 4; n++) {
        const int row = c0 + n * 16 + (l & 15);
        bfr[n] = *(const bf16x8*)((const char*)lB + row * 128 + (kbyte ^ ((row & 7) << 4)));
      }
#pragma unroll
      for (int m = 0; m < 4; m++)
#pragma unroll
        for (int n = 0; n < 4; n++)
          acc[m][n] = __builtin_amdgcn_mfma_f32_16x16x32_bf16(af[m], bfr[n], acc[m][n], 0, 0, 0);
    }
    __syncthreads();
  }

  // -------- epilogue: exp + diagonal mask + row/col partial sums --------
  float rsum[4][4];
  float csum[4];
#pragma unroll
  for (int m = 0; m < 4; m++)
#pragma unroll
    for (int j = 0; j < 4; j++) rsum[m][j] = 0.f;
#pragma unroll
  for (int n = 0; n < 4; n++) csum[n] = 0.f;

  const int rowoff = (l >> 4) * 4, col16 = l & 15;
  const int growbase = rb * 128 + r0 + rowoff;
  const int gcolbase = cb * 128 + c0 + col16;
#pragma unroll
  for (int m = 0; m < 4; m++) {
#pragma unroll
    for (int n = 0; n < 4; n++) {
#pragma unroll
      for (int j = 0; j < 4; j++) {
        const int grow = growbase + m * 16 + j;
        const int gcol = gcolbase + n * 16;
        const float e = (grow == gcol) ? 0.f : exp2f(acc[m][n][j] * EXPSCALE);
        rsum[m][j] += e;
        csum[n] += e;
      }
    }
  }
  // row sums: reduce across the 16 column-lanes
#pragma unroll
  for (int m = 0; m < 4; m++)
#pragma unroll
    for (int j = 0; j < 4; j++) {
      float v = rsum[m][j];
      v += __shfl_xor(v, 1); v += __shfl_xor(v, 2);
      v += __shfl_xor(v, 4); v += __shfl_xor(v, 8);
      rsum[m][j] = v;
    }
  // col sums: reduce across the 4 row lane-groups
#pragma unroll
  for (int n = 0; n < 4; n++) {
    float v = csum[n];
    v += __shfl_xor(v, 16); v += __shfl_xor(v, 32);
    csum[n] = v;
  }

  float* rowsumLDS = (float*)lA;            // [2 wave-cols][128 rows]
  float* colsumLDS = ((float*)lA) + 256;    // [2 wave-rows][128 cols]
  if (col16 == 0) {
#pragma unroll
    for (int m = 0; m < 4; m++)
#pragma unroll
      for (int j = 0; j < 4; j++)
        rowsumLDS[wc * 128 + r0 + m * 16 + rowoff + j] = rsum[m][j];
  }
  if ((l >> 4) == 0) {
#pragma unroll
    for (int n = 0; n < 4; n++)
      colsumLDS[wr * 128 + c0 + n * 16 + col16] = csum[n];
  }
  __syncthreads();
  if (t < 128) {
    const float rs = rowsumLDS[t] + rowsumLDS[128 + t];
    partial[(size_t)cb * N2 + rb * 128 + t] = rs;
    if (rb != cb) {
      const float cs = colsumLDS[t] + colsumLDS[128 + t];
      partial[(size_t)rb * N2 + cb * 128 + t] = cs;
    }
  }
}

// ---------------- Kernel C1: per-row denom = sum of 64 partials; log; block sum -----------
__device__ inline float blockReduce(float v, float* sred) {
#pragma unroll
  for (int o = 32; o > 0; o >>= 1) v += __shfl_xor(v, o);
  const int lane = threadIdx.x & 63, wid = threadIdx.x >> 6;
  if (lane == 0) sred[wid] = v;
  __syncthreads();
  v = sred[0] + sred[1] + sred[2] + sred[3];
  __syncthreads();
  return v;
}

__global__ __launch_bounds__(256) void kred1(const float* __restrict__ partial,
                                             float* __restrict__ bsum) {
  const int r = blockIdx.x * 256 + threadIdx.x;
  float d = 0.f;
#pragma unroll 8
  for (int cbx = 0; cbx < 64; ++cbx) d += partial[(size_t)cbx * N2 + r];
  float v = logf(d);
  __shared__ float sred[4];
  v = blockReduce(v, sred);
  if (threadIdx.x == 0) bsum[blockIdx.x] = v;
}

// ---------------- Kernel C2: final scalar -------------------------------------------------
__global__ __launch_bounds__(256) void kred2(const float* __restrict__ bsum,
                                             const float* __restrict__ pos,
                                             float* __restrict__ out) {
  const int t = threadIdx.x;
  float v = (t < 32) ? bsum[t] : 0.f;
  float p = 0.f;
  for (int k = t; k < BSZ; k += 256) p += pos[k];
  __shared__ float sred[4];
  v = blockReduce(v, sred);
  p = blockReduce(p, sred);
  if (t == 0) out[0] = (v - 2.0f * p / TEMPV) / (float)N2;
}

extern "C" void kernel_launch(void* const* d_in, const int* in_sizes, int n_in,
                              void* d_out, int out_size, void* d_ws, size_t ws_size,
                              hipStream_t stream) {
  const float* ei = (const float*)d_in[0];
  const float* ej = (const float*)d_in[1];
  char* ws = (char*)d_ws;
  unsigned short* reps = (unsigned short*)ws;                       // 16 MB bf16 [8192][1024]
  float* partial = (float*)(ws + (size_t)16 * 1024 * 1024);         // 2 MB  [64][8192]
  float* pos = (float*)(ws + (size_t)18 * 1024 * 1024);             // 16 KB [4096]
  float* bsum = (float*)(ws + (size_t)18 * 1024 * 1024 + 16384);    // 128 B [32]

  knorm<<<BSZ, 256, 0, stream>>>(ei, ej, reps, pos);
  kgemm<<<2080, 256, 0, stream>>>((const short*)reps, partial);
  kred1<<<32, 256, 0, stream>>>(partial, bsum);
  kred2<<<1, 256, 0, stream>>>(bsum, pos, (float*)d_out);
}

// Round 2
// 126.331 us; speedup vs baseline: 1.0493x; 1.0493x over previous
//
#include <hip/hip_runtime.h>

#define BSZ 4096
#define D 1024
#define N2 8192
#define TEMPV 0.5f
// exp(x/T) = exp2(x * log2(e)/T)
#define EXPSCALE 2.8853900817779268f
#define NTB 32      // 8192 / 256 tiles per dim
#define NBLK 528    // 32*33/2 upper-triangle blocks

typedef __attribute__((ext_vector_type(8))) short bf16x8;
typedef __attribute__((ext_vector_type(4))) float f32x4;

__device__ inline unsigned short f2bf(float x) {
  unsigned int u = __float_as_uint(x);
  u += 0x7fffu + ((u >> 16) & 1u);   // round-to-nearest-even
  return (unsigned short)(u >> 16);
}

__device__ inline void gload16(const void* g, void* l) {
  __builtin_amdgcn_global_load_lds(
      (const __attribute__((address_space(1))) void*)g,
      (__attribute__((address_space(3))) void*)l, 16, 0, 0);
}

// ---------------- Kernel A: L2-normalize rows, emit bf16 reps + pos dot ----------------
__global__ __launch_bounds__(256) void knorm(const float* __restrict__ ei,
                                             const float* __restrict__ ej,
                                             unsigned short* __restrict__ reps,
                                             float* __restrict__ pos) {
  const int r = blockIdx.x;
  const int t = threadIdx.x;
  const float4 vi = ((const float4*)(ei + (size_t)r * D))[t];
  const float4 vj = ((const float4*)(ej + (size_t)r * D))[t];
  float ssi = vi.x * vi.x + vi.y * vi.y + vi.z * vi.z + vi.w * vi.w;
  float ssj = vj.x * vj.x + vj.y * vj.y + vj.z * vj.z + vj.w * vj.w;
  float sij = vi.x * vj.x + vi.y * vj.y + vi.z * vj.z + vi.w * vj.w;
#pragma unroll
  for (int o = 32; o > 0; o >>= 1) {
    ssi += __shfl_xor(ssi, o);
    ssj += __shfl_xor(ssj, o);
    sij += __shfl_xor(sij, o);
  }
  __shared__ float red[12];
  const int lane = t & 63, wid = t >> 6;
  if (lane == 0) { red[wid * 3] = ssi; red[wid * 3 + 1] = ssj; red[wid * 3 + 2] = sij; }
  __syncthreads();
  ssi = red[0] + red[3] + red[6] + red[9];
  ssj = red[1] + red[4] + red[7] + red[10];
  sij = red[2] + red[5] + red[8] + red[11];
  const float inv_i = rsqrtf(fmaxf(ssi, 1e-24f));
  const float inv_j = rsqrtf(fmaxf(ssj, 1e-24f));
  ushort4 ui, uj;
  ui.x = f2bf(vi.x * inv_i); ui.y = f2bf(vi.y * inv_i);
  ui.z = f2bf(vi.z * inv_i); ui.w = f2bf(vi.w * inv_i);
  uj.x = f2bf(vj.x * inv_j); uj.y = f2bf(vj.y * inv_j);
  uj.z = f2bf(vj.z * inv_j); uj.w = f2bf(vj.w * inv_j);
  *((ushort4*)(reps + (size_t)r * D) + t) = ui;
  *((ushort4*)(reps + (size_t)(BSZ + r) * D) + t) = uj;
  if (t == 0) pos[r] = sij * inv_i * inv_j;
}

// ---------------- Kernel B: 256x256 upper-triangle tiles, dbuf + counted vmcnt ----------
// 8 waves (2M x 4N), wave tile 128x64, BK=64, 128 KiB dynamic LDS.
__global__ __launch_bounds__(512, 2) void kgemm2(const short* __restrict__ reps,
                                                 float* __restrict__ partial) {
  extern __shared__ char smem[];
  short* lA0 = (short*)smem;                  // 32 KB  [256][64]
  short* lB0 = (short*)(smem + 32768);        // 32 KB
  short* lA1 = (short*)(smem + 65536);
  short* lB1 = (short*)(smem + 98304);

  // triangle decode: bid -> (rb, cb), cb >= rb
  int rem = blockIdx.x;
  int rb = 0;
  while (rem >= NTB - rb) { rem -= NTB - rb; rb++; }
  const int cb = rb + rem;

  const int t = threadIdx.x;
  const int l = t & 63, w = t >> 6;
  const int wr = w >> 2, wc = w & 3;          // 2 x 4 wave grid

  f32x4 acc[8][4];
  const f32x4 zero4 = {0.f, 0.f, 0.f, 0.f};
#pragma unroll
  for (int m = 0; m < 8; m++)
#pragma unroll
    for (int n = 0; n < 4; n++) acc[m][n] = zero4;

  // staging: per inst, 512 lanes x 16B = 64 rows of 128B; 4 insts cover 256 rows
  const int srow8 = w * 8 + (l >> 3);          // row within 64-row inst group
  const int schunk = (l & 7) ^ (l >> 3);       // pre-swizzled source 16B chunk
  const size_t arow0 = (size_t)rb * 256;
  const size_t brow0 = (size_t)cb * 256;

#define STAGE(kt, dA, dB)                                                     \
  {                                                                           \
    const int k0_ = (kt) * 64 + schunk * 8;                                   \
    _Pragma("unroll") for (int i_ = 0; i_ < 4; i_++) {                        \
      const int r_ = i_ * 64 + srow8;                                         \
      gload16(reps + (arow0 + r_) * D + k0_, (dA) + (size_t)(i_ * 64 + w * 8) * 64); \
      gload16(reps + (brow0 + r_) * D + k0_, (dB) + (size_t)(i_ * 64 + w * 8) * 64); \
    }                                                                         \
  }

  STAGE(0, lA0, lB0);

  const int swz = (l & 7) << 4;
  const int q16 = ((l >> 4) & 3) * 16;
  const int arow = wr * 128 + (l & 15);
  const int brow = wc * 64 + (l & 15);
  const int offk0 = (q16) ^ swz;
  const int offk1 = (64 + q16) ^ swz;

#pragma unroll 1
  for (int kt = 0; kt < 16; ++kt) {
    const int cur = kt & 1;
    const char* bA = (const char*)(cur ? lA1 : lA0);
    const char* bB = (const char*)(cur ? lB1 : lB0);
    short* nA = cur ? lA0 : lA1;
    short* nB = cur ? lB0 : lB1;
    if (kt < 15) {
      STAGE(kt + 1, nA, nB);
      asm volatile("s_waitcnt vmcnt(8)" ::: "memory");   // tile kt landed; kt+1 in flight
    } else {
      asm volatile("s_waitcnt vmcnt(0)" ::: "memory");
    }
    __builtin_amdgcn_s_barrier();
    asm volatile("" ::: "memory");

    bf16x8 bfrag[4][2];
#pragma unroll
    for (int n = 0; n < 4; n++) {
      const int r = brow + n * 16;
      bfrag[n][0] = *(const bf16x8*)(bB + r * 128 + offk0);
      bfrag[n][1] = *(const bf16x8*)(bB + r * 128 + offk1);
    }
#pragma unroll
    for (int q = 0; q < 4; q++) {
      bf16x8 af[2][2];
#pragma unroll
      for (int m2 = 0; m2 < 2; m2++) {
        const int r = arow + (q * 2 + m2) * 16;
        af[m2][0] = *(const bf16x8*)(bA + r * 128 + offk0);
        af[m2][1] = *(const bf16x8*)(bA + r * 128 + offk1);
      }
      __builtin_amdgcn_s_setprio(1);
#pragma unroll
      for (int kk = 0; kk < 2; kk++)
#pragma unroll
        for (int m2 = 0; m2 < 2; m2++)
#pragma unroll
          for (int n = 0; n < 4; n++)
            acc[q * 2 + m2][n] = __builtin_amdgcn_mfma_f32_16x16x32_bf16(
                af[m2][kk], bfrag[n][kk], acc[q * 2 + m2][n], 0, 0, 0);
      __builtin_amdgcn_s_setprio(0);
    }
    __builtin_amdgcn_s_barrier();
    asm volatile("" ::: "memory");
  }

  // -------- epilogue: exp + diagonal mask + row/col partial sums --------
  float rsum[8][4];
  float csum[4];
#pragma unroll
  for (int m = 0; m < 8; m++)
#pragma unroll
    for (int j = 0; j < 4; j++) rsum[m][j] = 0.f;
#pragma unroll
  for (int n = 0; n < 4; n++) csum[n] = 0.f;

  const int col16 = l & 15, rgp = (l >> 4) & 3;
  const bool diag = (rb == cb);
  const int growbase = wr * 128 + rgp * 4;     // + m*16 + j  (within tile)
  const int gcolbase = wc * 64 + col16;        // + n*16      (within tile)
#pragma unroll
  for (int m = 0; m < 8; m++) {
#pragma unroll
    for (int n = 0; n < 4; n++) {
#pragma unroll
      for (int j = 0; j < 4; j++) {
        const float e = (diag && (growbase + m * 16 + j) == (gcolbase + n * 16))
                            ? 0.f
                            : exp2f(acc[m][n][j] * EXPSCALE);
        rsum[m][j] += e;
        csum[n] += e;
      }
    }
  }
#pragma unroll
  for (int m = 0; m < 8; m++)
#pragma unroll
    for (int j = 0; j < 4; j++) {
      float v = rsum[m][j];
      v += __shfl_xor(v, 1); v += __shfl_xor(v, 2);
      v += __shfl_xor(v, 4); v += __shfl_xor(v, 8);
      rsum[m][j] = v;
    }
#pragma unroll
  for (int n = 0; n < 4; n++) {
    float v = csum[n];
    v += __shfl_xor(v, 16); v += __shfl_xor(v, 32);
    csum[n] = v;
  }

  float* rS = (float*)smem;            // [4 wc][256 rows]
  float* cS = ((float*)smem) + 1024;   // [2 wr][256 cols]
  if (col16 == 0) {
#pragma unroll
    for (int m = 0; m < 8; m++)
#pragma unroll
      for (int j = 0; j < 4; j++)
        rS[wc * 256 + wr * 128 + m * 16 + rgp * 4 + j] = rsum[m][j];
  }
  if (rgp == 0) {
#pragma unroll
    for (int n = 0; n < 4; n++)
      cS[wr * 256 + wc * 64 + n * 16 + col16] = csum[n];
  }
  __syncthreads();
  if (t < 256) {
    const float rs = rS[t] + rS[256 + t] + rS[512 + t] + rS[768 + t];
    partial[(size_t)cb * N2 + rb * 256 + t] = rs;
    if (!diag) {
      const float cs = cS[t] + cS[256 + t];
      partial[(size_t)rb * N2 + cb * 256 + t] = cs;
    }
  }
}

// ---------------- Kernel C1: per-row denom = sum of 32 partials; log; block sum -----------
__device__ inline float blockReduce(float v, float* sred) {
#pragma unroll
  for (int o = 32; o > 0; o >>= 1) v += __shfl_xor(v, o);
  const int lane = threadIdx.x & 63, wid = threadIdx.x >> 6;
  if (lane == 0) sred[wid] = v;
  __syncthreads();
  v = sred[0] + sred[1] + sred[2] + sred[3];
  __syncthreads();
  return v;
}

__global__ __launch_bounds__(256) void kred1(const float* __restrict__ partial,
                                             float* __restrict__ bsum) {
  const int r = blockIdx.x * 256 + threadIdx.x;
  float d = 0.f;
#pragma unroll 8
  for (int cbx = 0; cbx < 32; ++cbx) d += partial[(size_t)cbx * N2 + r];
  float v = logf(d);
  __shared__ float sred[4];
  v = blockReduce(v, sred);
  if (threadIdx.x == 0) bsum[blockIdx.x] = v;
}

// ---------------- Kernel C2: final scalar -------------------------------------------------
__global__ __launch_bounds__(256) void kred2(const float* __restrict__ bsum,
                                             const float* __restrict__ pos,
                                             float* __restrict__ out) {
  const int t = threadIdx.x;
  float v = (t < 32) ? bsum[t] : 0.f;
  float p = 0.f;
  for (int k = t; k < BSZ; k += 256) p += pos[k];
  __shared__ float sred[4];
  v = blockReduce(v, sred);
  p = blockReduce(p, sred);
  if (t == 0) out[0] = (v - 2.0f * p / TEMPV) / (float)N2;
}

extern "C" void kernel_launch(void* const* d_in, const int* in_sizes, int n_in,
                              void* d_out, int out_size, void* d_ws, size_t ws_size,
                              hipStream_t stream) {
  const float* ei = (const float*)d_in[0];
  const float* ej = (const float*)d_in[1];
  char* ws = (char*)d_ws;
  unsigned short* reps = (unsigned short*)ws;                       // 16 MB bf16 [8192][1024]
  float* partial = (float*)(ws + (size_t)16 * 1024 * 1024);         // 1 MB  [32][8192]
  float* pos = (float*)(ws + (size_t)18 * 1024 * 1024);             // 16 KB [4096]
  float* bsum = (float*)(ws + (size_t)18 * 1024 * 1024 + 16384);    // 128 B [32]

  (void)hipFuncSetAttribute((const void*)kgemm2,
                            hipFuncAttributeMaxDynamicSharedMemorySize, 131072);

  knorm<<<BSZ, 256, 0, stream>>>(ei, ej, reps, pos);
  kgemm2<<<NBLK, 512, 131072, stream>>>((const short*)reps, partial);
  kred1<<<32, 256, 0, stream>>>(partial, bsum);
  kred2<<<1, 256, 0, stream>>>(bsum, pos, (float*)d_out);
}

// Round 3
// 121.041 us; speedup vs baseline: 1.0951x; 1.0437x over previous
//
#include <hip/hip_runtime.h>

#define BSZ 4096
#define D 1024
#define N2 8192
#define TEMPV 0.5f
// exp(x/T) = exp2(x * log2(e)/T)
#define EXPSCALE 2.8853900817779268f
#define NTB 32      // 8192 / 256 tiles per dim
#define NBLK 528    // 32*33/2 upper-triangle blocks

typedef __attribute__((ext_vector_type(8))) short bf16x8;
typedef __attribute__((ext_vector_type(4))) float f32x4;

__device__ inline unsigned short f2bf(float x) {
  unsigned int u = __float_as_uint(x);
  u += 0x7fffu + ((u >> 16) & 1u);   // round-to-nearest-even
  return (unsigned short)(u >> 16);
}

__device__ inline void gload16(const void* g, void* l) {
  __builtin_amdgcn_global_load_lds(
      (const __attribute__((address_space(1))) void*)g,
      (__attribute__((address_space(3))) void*)l, 16, 0, 0);
}

// ---------------- Kernel A: L2-normalize rows, emit bf16 reps + pos dot ----------------
__global__ __launch_bounds__(256) void knorm(const float* __restrict__ ei,
                                             const float* __restrict__ ej,
                                             unsigned short* __restrict__ reps,
                                             float* __restrict__ pos) {
  const int r = blockIdx.x;
  const int t = threadIdx.x;
  const float4 vi = ((const float4*)(ei + (size_t)r * D))[t];
  const float4 vj = ((const float4*)(ej + (size_t)r * D))[t];
  float ssi = vi.x * vi.x + vi.y * vi.y + vi.z * vi.z + vi.w * vi.w;
  float ssj = vj.x * vj.x + vj.y * vj.y + vj.z * vj.z + vj.w * vj.w;
  float sij = vi.x * vj.x + vi.y * vj.y + vi.z * vj.z + vi.w * vj.w;
#pragma unroll
  for (int o = 32; o > 0; o >>= 1) {
    ssi += __shfl_xor(ssi, o);
    ssj += __shfl_xor(ssj, o);
    sij += __shfl_xor(sij, o);
  }
  __shared__ float red[12];
  const int lane = t & 63, wid = t >> 6;
  if (lane == 0) { red[wid * 3] = ssi; red[wid * 3 + 1] = ssj; red[wid * 3 + 2] = sij; }
  __syncthreads();
  ssi = red[0] + red[3] + red[6] + red[9];
  ssj = red[1] + red[4] + red[7] + red[10];
  sij = red[2] + red[5] + red[8] + red[11];
  const float inv_i = rsqrtf(fmaxf(ssi, 1e-24f));
  const float inv_j = rsqrtf(fmaxf(ssj, 1e-24f));
  ushort4 ui, uj;
  ui.x = f2bf(vi.x * inv_i); ui.y = f2bf(vi.y * inv_i);
  ui.z = f2bf(vi.z * inv_i); ui.w = f2bf(vi.w * inv_i);
  uj.x = f2bf(vj.x * inv_j); uj.y = f2bf(vj.y * inv_j);
  uj.z = f2bf(vj.z * inv_j); uj.w = f2bf(vj.w * inv_j);
  *((ushort4*)(reps + (size_t)r * D) + t) = ui;
  *((ushort4*)(reps + (size_t)(BSZ + r) * D) + t) = uj;
  if (t == 0) pos[r] = sij * inv_i * inv_j;
}

// ---------------- Kernel B: 256x256 triangle tiles, 4-phase interleave, counted vmcnt ----
// 8 waves (2M x 4N), wave tile 128x64, BK=64, 128 KiB dynamic LDS (2 buffers).
// Staging pipeline 2 tiles deep; per-wave load ledger (8 gload_lds per K-tile):
//   iter t: p0 issues A-chunks{1,3}(t+1); p1 issues B{0..3}(t+2); p2 issues A{0,2}(t+2)
//   waits: end-p1 vmcnt(12) (covers A{1,3}(t) for p2/p3 reads),
//          end-p3 vmcnt(8)  (covers B(t+1)+A{0,2}(t+1) for next-iter p0/p1 reads)
#define BARRIER() do { __builtin_amdgcn_s_barrier(); asm volatile("" ::: "memory"); } while (0)
#define STR2(x) #x
#define WAITV(n) asm volatile("s_waitcnt vmcnt(" STR2(n) ")" ::: "memory")

#define SG_A(ii, ktv, dst) gload16(reps + (arow0 + (ii) * 64 + srow8) * D + (ktv) * 64 + schunk * 8, \
                                   (dst) + (size_t)((ii) * 64 + w * 8) * 64)
#define SG_B(ii, ktv, dst) gload16(reps + (brow0 + (ii) * 64 + srow8) * D + (ktv) * 64 + schunk * 8, \
                                   (dst) + (size_t)((ii) * 64 + w * 8) * 64)

#define PH0_READB()                                                     \
  _Pragma("unroll") for (int n = 0; n < 4; n++) {                       \
    const char* rp = bB + (brow + n * 16) * 128;                        \
    bfr[n][0] = *(const bf16x8*)(rp + offk0);                           \
    bfr[n][1] = *(const bf16x8*)(rp + offk1);                           \
  }

#define PH(p, STAGECODE, TAILCODE)                                      \
  {                                                                     \
    bf16x8 af0a, af0b, af1a, af1b;                                      \
    {                                                                   \
      const char* rp0 = bA + (arow + (2 * (p)) * 16) * 128;             \
      const char* rp1 = bA + (arow + (2 * (p) + 1) * 16) * 128;         \
      af0a = *(const bf16x8*)(rp0 + offk0);                             \
      af0b = *(const bf16x8*)(rp0 + offk1);                             \
      af1a = *(const bf16x8*)(rp1 + offk0);                             \
      af1b = *(const bf16x8*)(rp1 + offk1);                             \
    }                                                                   \
    STAGECODE;                                                          \
    BARRIER();                                                          \
    __builtin_amdgcn_s_setprio(1);                                      \
    _Pragma("unroll") for (int n = 0; n < 4; n++) {                     \
      acc[2 * (p)][n] = __builtin_amdgcn_mfma_f32_16x16x32_bf16(af0a, bfr[n][0], acc[2 * (p)][n], 0, 0, 0); \
      acc[2 * (p) + 1][n] = __builtin_amdgcn_mfma_f32_16x16x32_bf16(af1a, bfr[n][0], acc[2 * (p) + 1][n], 0, 0, 0); \
    }                                                                   \
    _Pragma("unroll") for (int n = 0; n < 4; n++) {                     \
      acc[2 * (p)][n] = __builtin_amdgcn_mfma_f32_16x16x32_bf16(af0b, bfr[n][1], acc[2 * (p)][n], 0, 0, 0); \
      acc[2 * (p) + 1][n] = __builtin_amdgcn_mfma_f32_16x16x32_bf16(af1b, bfr[n][1], acc[2 * (p) + 1][n], 0, 0, 0); \
    }                                                                   \
    __builtin_amdgcn_s_setprio(0);                                      \
    TAILCODE;                                                           \
    BARRIER();                                                          \
  }

#define DO_ITER(ktv, S0, S12, W1, W3)                                   \
  {                                                                     \
    const int cur = (ktv) & 1;                                          \
    const char* bA = (const char*)(cur ? lA1 : lA0);                    \
    const char* bB = (const char*)(cur ? lB1 : lB0);                    \
    short* nxA = cur ? lA0 : lA1;                                       \
    short* sA = cur ? lA1 : lA0;                                        \
    short* sB = cur ? lB1 : lB0;                                        \
    bf16x8 bfr[4][2];                                                   \
    PH0_READB();                                                        \
    PH(0, if (S0) { SG_A(1, (ktv) + 1, nxA); SG_A(3, (ktv) + 1, nxA); }, ) \
    PH(1, if (S12) { SG_B(0, (ktv) + 2, sB); SG_B(1, (ktv) + 2, sB);    \
                     SG_B(2, (ktv) + 2, sB); SG_B(3, (ktv) + 2, sB); }, \
       WAITV(W1))                                                       \
    PH(2, if (S12) { SG_A(0, (ktv) + 2, sA); SG_A(2, (ktv) + 2, sA); }, ) \
    PH(3, , WAITV(W3))                                                  \
  }

__global__ __launch_bounds__(512, 2) void kgemm2(const short* __restrict__ reps,
                                                 float* __restrict__ partial) {
  extern __shared__ char smem[];
  short* lA0 = (short*)smem;                  // 32 KB  [256][64]
  short* lB0 = (short*)(smem + 32768);        // 32 KB
  short* lA1 = (short*)(smem + 65536);
  short* lB1 = (short*)(smem + 98304);

  // triangle decode: bid -> (rb, cb), cb >= rb
  int rem = blockIdx.x;
  int rb = 0;
  while (rem >= NTB - rb) { rem -= NTB - rb; rb++; }
  const int cb = rb + rem;

  const int t = threadIdx.x;
  const int l = t & 63, w = t >> 6;
  const int wr = w >> 2, wc = w & 3;          // 2 x 4 wave grid

  f32x4 acc[8][4];
  const f32x4 zero4 = {0.f, 0.f, 0.f, 0.f};
#pragma unroll
  for (int m = 0; m < 8; m++)
#pragma unroll
    for (int n = 0; n < 4; n++) acc[m][n] = zero4;

  // staging addressing: per inst, one wave covers 8 rows x 128B (1 KB contiguous LDS)
  const int srow8 = w * 8 + (l >> 3);          // row within 64-row inst chunk
  const int schunk = (l & 7) ^ (l >> 3);       // pre-swizzled source 16B chunk
  const size_t arow0 = (size_t)rb * 256;
  const size_t brow0 = (size_t)cb * 256;

  // read-side addressing (XOR swizzle matches pre-swizzled staging)
  const int swz = (l & 7) << 4;
  const int q16 = ((l >> 4) & 3) * 16;
  const int arow = wr * 128 + (l & 15);
  const int brow = wc * 64 + (l & 15);
  const int offk0 = (q16) ^ swz;
  const int offk1 = (64 + q16) ^ swz;

  // ---- prologue: stage in steady-state ledger order (14 loads/wave) ----
  SG_B(0, 0, lB0); SG_B(1, 0, lB0); SG_B(2, 0, lB0); SG_B(3, 0, lB0);
  SG_A(0, 0, lA0); SG_A(2, 0, lA0);
  SG_A(1, 0, lA0); SG_A(3, 0, lA0);
  SG_B(0, 1, lB1); SG_B(1, 1, lB1); SG_B(2, 1, lB1); SG_B(3, 1, lB1);
  SG_A(0, 1, lA1); SG_A(2, 1, lA1);
  WAITV(8);
  BARRIER();

#pragma unroll 1
  for (int kt = 0; kt < 14; ++kt) DO_ITER(kt, 1, 1, 12, 8)
  DO_ITER(14, 1, 0, 8, 2)
  DO_ITER(15, 0, 0, 0, 0)

  // -------- epilogue: exp + diagonal mask + row/col partial sums --------
  float rsum[8][4];
  float csum[4];
#pragma unroll
  for (int m = 0; m < 8; m++)
#pragma unroll
    for (int j = 0; j < 4; j++) rsum[m][j] = 0.f;
#pragma unroll
  for (int n = 0; n < 4; n++) csum[n] = 0.f;

  const int col16 = l & 15, rgp = (l >> 4) & 3;
  const bool diag = (rb == cb);
  const int growbase = wr * 128 + rgp * 4;     // + m*16 + j  (within tile)
  const int gcolbase = wc * 64 + col16;        // + n*16      (within tile)
#pragma unroll
  for (int m = 0; m < 8; m++) {
#pragma unroll
    for (int n = 0; n < 4; n++) {
#pragma unroll
      for (int j = 0; j < 4; j++) {
        const float e = (diag && (growbase + m * 16 + j) == (gcolbase + n * 16))
                            ? 0.f
                            : exp2f(acc[m][n][j] * EXPSCALE);
        rsum[m][j] += e;
        csum[n] += e;
      }
    }
  }
#pragma unroll
  for (int m = 0; m < 8; m++)
#pragma unroll
    for (int j = 0; j < 4; j++) {
      float v = rsum[m][j];
      v += __shfl_xor(v, 1); v += __shfl_xor(v, 2);
      v += __shfl_xor(v, 4); v += __shfl_xor(v, 8);
      rsum[m][j] = v;
    }
#pragma unroll
  for (int n = 0; n < 4; n++) {
    float v = csum[n];
    v += __shfl_xor(v, 16); v += __shfl_xor(v, 32);
    csum[n] = v;
  }

  float* rS = (float*)smem;            // [4 wc][256 rows]
  float* cS = ((float*)smem) + 1024;   // [2 wr][256 cols]
  if (col16 == 0) {
#pragma unroll
    for (int m = 0; m < 8; m++)
#pragma unroll
      for (int j = 0; j < 4; j++)
        rS[wc * 256 + wr * 128 + m * 16 + rgp * 4 + j] = rsum[m][j];
  }
  if (rgp == 0) {
#pragma unroll
    for (int n = 0; n < 4; n++)
      cS[wr * 256 + wc * 64 + n * 16 + col16] = csum[n];
  }
  __syncthreads();
  if (t < 256) {
    const float rs = rS[t] + rS[256 + t] + rS[512 + t] + rS[768 + t];
    partial[(size_t)cb * N2 + rb * 256 + t] = rs;
    if (!diag) {
      const float cs = cS[t] + cS[256 + t];
      partial[(size_t)rb * N2 + cb * 256 + t] = cs;
    }
  }
}

// ---------------- Kernel C1: per-row denom = sum of 32 partials; log; block sum -----------
__device__ inline float blockReduce(float v, float* sred) {
#pragma unroll
  for (int o = 32; o > 0; o >>= 1) v += __shfl_xor(v, o);
  const int lane = threadIdx.x & 63, wid = threadIdx.x >> 6;
  if (lane == 0) sred[wid] = v;
  __syncthreads();
  v = sred[0] + sred[1] + sred[2] + sred[3];
  __syncthreads();
  return v;
}

__global__ __launch_bounds__(256) void kred1(const float* __restrict__ partial,
                                             float* __restrict__ bsum) {
  const int r = blockIdx.x * 256 + threadIdx.x;
  float d = 0.f;
#pragma unroll 8
  for (int cbx = 0; cbx < 32; ++cbx) d += partial[(size_t)cbx * N2 + r];
  float v = logf(d);
  __shared__ float sred[4];
  v = blockReduce(v, sred);
  if (threadIdx.x == 0) bsum[blockIdx.x] = v;
}

// ---------------- Kernel C2: final scalar -------------------------------------------------
__global__ __launch_bounds__(256) void kred2(const float* __restrict__ bsum,
                                             const float* __restrict__ pos,
                                             float* __restrict__ out) {
  const int t = threadIdx.x;
  float v = (t < 32) ? bsum[t] : 0.f;
  float p = 0.f;
  for (int k = t; k < BSZ; k += 256) p += pos[k];
  __shared__ float sred[4];
  v = blockReduce(v, sred);
  p = blockReduce(p, sred);
  if (t == 0) out[0] = (v - 2.0f * p / TEMPV) / (float)N2;
}

extern "C" void kernel_launch(void* const* d_in, const int* in_sizes, int n_in,
                              void* d_out, int out_size, void* d_ws, size_t ws_size,
                              hipStream_t stream) {
  const float* ei = (const float*)d_in[0];
  const float* ej = (const float*)d_in[1];
  char* ws = (char*)d_ws;
  unsigned short* reps = (unsigned short*)ws;                       // 16 MB bf16 [8192][1024]
  float* partial = (float*)(ws + (size_t)16 * 1024 * 1024);         // 1 MB  [32][8192]
  float* pos = (float*)(ws + (size_t)18 * 1024 * 1024);             // 16 KB [4096]
  float* bsum = (float*)(ws + (size_t)18 * 1024 * 1024 + 16384);    // 128 B [32]

  (void)hipFuncSetAttribute((const void*)kgemm2,
                            hipFuncAttributeMaxDynamicSharedMemorySize, 131072);

  knorm<<<BSZ, 256, 0, stream>>>(ei, ej, reps, pos);
  kgemm2<<<NBLK, 512, 131072, stream>>>((const short*)reps, partial);
  kred1<<<32, 256, 0, stream>>>(partial, bsum);
  kred2<<<1, 256, 0, stream>>>(bsum, pos, (float*)d_out);
}

// Round 4
// 113.128 us; speedup vs baseline: 1.1717x; 1.0699x over previous
//
#include <hip/hip_runtime.h>

#define BSZ 4096
#define D 1024
#define N2 8192
#define TEMPV 0.5f
// exp(x/T) = exp2(x * log2(e)/T)
#define EXPSCALE 2.8853900817779268f
#define NTB 32      // 8192 / 256 tiles per dim
#define NBLK 528    // 32*33/2 upper-triangle blocks

typedef __attribute__((ext_vector_type(8))) short bf16x8;
typedef __attribute__((ext_vector_type(4))) float f32x4;

__device__ inline unsigned short f2bf(float x) {
  unsigned int u = __float_as_uint(x);
  u += 0x7fffu + ((u >> 16) & 1u);   // round-to-nearest-even
  return (unsigned short)(u >> 16);
}

__device__ inline void gload16(const void* g, void* l) {
  __builtin_amdgcn_global_load_lds(
      (const __attribute__((address_space(1))) void*)g,
      (__attribute__((address_space(3))) void*)l, 16, 0, 0);
}

// ---------------- Kernel A: L2-normalize rows, emit bf16 reps + pos dot ----------------
__global__ __launch_bounds__(256) void knorm(const float* __restrict__ ei,
                                             const float* __restrict__ ej,
                                             unsigned short* __restrict__ reps,
                                             float* __restrict__ pos) {
  const int r = blockIdx.x;
  const int t = threadIdx.x;
  const float4 vi = ((const float4*)(ei + (size_t)r * D))[t];
  const float4 vj = ((const float4*)(ej + (size_t)r * D))[t];
  float ssi = vi.x * vi.x + vi.y * vi.y + vi.z * vi.z + vi.w * vi.w;
  float ssj = vj.x * vj.x + vj.y * vj.y + vj.z * vj.z + vj.w * vj.w;
  float sij = vi.x * vj.x + vi.y * vj.y + vi.z * vj.z + vi.w * vj.w;
#pragma unroll
  for (int o = 32; o > 0; o >>= 1) {
    ssi += __shfl_xor(ssi, o);
    ssj += __shfl_xor(ssj, o);
    sij += __shfl_xor(sij, o);
  }
  __shared__ float red[12];
  const int lane = t & 63, wid = t >> 6;
  if (lane == 0) { red[wid * 3] = ssi; red[wid * 3 + 1] = ssj; red[wid * 3 + 2] = sij; }
  __syncthreads();
  ssi = red[0] + red[3] + red[6] + red[9];
  ssj = red[1] + red[4] + red[7] + red[10];
  sij = red[2] + red[5] + red[8] + red[11];
  const float inv_i = rsqrtf(fmaxf(ssi, 1e-24f));
  const float inv_j = rsqrtf(fmaxf(ssj, 1e-24f));
  ushort4 ui, uj;
  ui.x = f2bf(vi.x * inv_i); ui.y = f2bf(vi.y * inv_i);
  ui.z = f2bf(vi.z * inv_i); ui.w = f2bf(vi.w * inv_i);
  uj.x = f2bf(vj.x * inv_j); uj.y = f2bf(vj.y * inv_j);
  uj.z = f2bf(vj.z * inv_j); uj.w = f2bf(vj.w * inv_j);
  *((ushort4*)(reps + (size_t)r * D) + t) = ui;
  *((ushort4*)(reps + (size_t)(BSZ + r) * D) + t) = uj;
  if (t == 0) pos[r] = sij * inv_i * inv_j;
}

// ---------------- Kernel B: 256x256 triangle tiles, read-ahead 4-phase pipeline ----------
// 8 waves (2M x 4N), wave tile 128x64, BK=64, 128 KiB LDS (A dbuf + B dbuf).
// Invariant: every MFMA cluster consumes registers loaded before the PREVIOUS barrier.
// Stage ledger per wave per tile (4+4 gloads): A(t+1)x4 @ph1, B(t+2)x4 @ph3,
// single vmcnt(4) @ph3 tail (leaves B(t+2)x4 in flight; retires A(t+1)+B(t+1)).
#define BARRIER() do { __builtin_amdgcn_s_barrier(); asm volatile("" ::: "memory"); } while (0)
#define STR2(x) #x
#define WAITV(n) asm volatile("s_waitcnt vmcnt(" STR2(n) ")" ::: "memory")

#define SG_A(ii, ktv, dst) gload16(reps + (arow0 + (ii) * 64 + srow8) * D + (ktv) * 64 + schunk * 8, \
                                   (dst) + (size_t)((ii) * 64 + w * 8) * 64)
#define SG_B(ii, ktv, dst) gload16(reps + (brow0 + (ii) * 64 + srow8) * D + (ktv) * 64 + schunk * 8, \
                                   (dst) + (size_t)((ii) * 64 + w * 8) * 64)

#define READ_AQ(buf, q) do {                                            \
    const char* rp0_ = (buf) + (arow + (2 * (q)) * 16) * 128;           \
    const char* rp1_ = (buf) + (arow + (2 * (q) + 1) * 16) * 128;       \
    af[0][0] = *(const bf16x8*)(rp0_ + offk0);                          \
    af[0][1] = *(const bf16x8*)(rp0_ + offk1);                          \
    af[1][0] = *(const bf16x8*)(rp1_ + offk0);                          \
    af[1][1] = *(const bf16x8*)(rp1_ + offk1);                          \
  } while (0)

#define READ_B2(buf, n) do {                                            \
    const char* rp_ = (buf) + (brow + (n) * 16) * 128;                  \
    bfr[n][0] = *(const bf16x8*)(rp_ + offk0);                          \
    bfr[n][1] = *(const bf16x8*)(rp_ + offk1);                          \
  } while (0)

// 16 MFMA; bfr[0..1] half first so ph1's fresh bfr[2..3] reads have cover.
#define MFMA_Q(q)                                                       \
  __builtin_amdgcn_s_setprio(1);                                        \
  _Pragma("unroll") for (int nh = 0; nh < 2; nh++)                      \
  _Pragma("unroll") for (int kk = 0; kk < 2; kk++)                      \
  _Pragma("unroll") for (int m2 = 0; m2 < 2; m2++)                      \
  _Pragma("unroll") for (int nn = 0; nn < 2; nn++) {                    \
    const int n_ = nh * 2 + nn;                                         \
    acc[2 * (q) + m2][n_] = __builtin_amdgcn_mfma_f32_16x16x32_bf16(    \
        af[m2][kk], bfr[n_][kk], acc[2 * (q) + m2][n_], 0, 0, 0);       \
  }                                                                     \
  __builtin_amdgcn_s_setprio(0);

#define DO_TILE(ktv, SA, SB, RDN, HASW, WV)                             \
  {                                                                     \
    const int cur = (ktv) & 1;                                          \
    const char* bA  = cur ? (const char*)lA1 : (const char*)lA0;        \
    const char* bB  = cur ? (const char*)lB1 : (const char*)lB0;        \
    const char* bAn = cur ? (const char*)lA0 : (const char*)lA1;        \
    const char* bBn = cur ? (const char*)lB0 : (const char*)lB1;        \
    short* stA = cur ? lA0 : lA1;                                       \
    short* stB = cur ? lB1 : lB0;                                       \
    /* ph1: q0 MFMA (ops from prev ph4); read bfr[2..3](t) + Aq1; stage A(t+1) */ \
    READ_B2(bB, 2); READ_B2(bB, 3);                                     \
    MFMA_Q(0);                                                          \
    READ_AQ(bA, 1);                                                     \
    if (SA) { SG_A(0, (ktv) + 1, stA); SG_A(1, (ktv) + 1, stA);         \
              SG_A(2, (ktv) + 1, stA); SG_A(3, (ktv) + 1, stA); }       \
    BARRIER();                                                          \
    /* ph2 */                                                           \
    MFMA_Q(1);                                                          \
    READ_AQ(bA, 2);                                                     \
    BARRIER();                                                          \
    /* ph3: stage B(t+2); counted wait */                               \
    MFMA_Q(2);                                                          \
    READ_AQ(bA, 3);                                                     \
    if (SB) { SG_B(0, (ktv) + 2, stB); SG_B(1, (ktv) + 2, stB);         \
              SG_B(2, (ktv) + 2, stB); SG_B(3, (ktv) + 2, stB); }       \
    if (HASW) { WAITV(WV); }                                            \
    BARRIER();                                                          \
    /* ph4: read next tile's Aq0 + bfr[0..1] */                         \
    MFMA_Q(3);                                                          \
    if (RDN) { READ_AQ(bAn, 0); READ_B2(bBn, 0); READ_B2(bBn, 1); }     \
    BARRIER();                                                          \
  }

__global__ __launch_bounds__(512, 2) void kgemm3(const short* __restrict__ reps,
                                                 float* __restrict__ partial) {
  extern __shared__ char smem[];
  short* lA0 = (short*)smem;                  // 32 KB  [256][64]
  short* lA1 = (short*)(smem + 32768);
  short* lB0 = (short*)(smem + 65536);
  short* lB1 = (short*)(smem + 98304);

  // XCD-aware swizzle (528 = 8 * 66, bijective), then triangle decode
  int bid = (int)blockIdx.x;
  bid = (bid & 7) * 66 + (bid >> 3);
  int rem = bid;
  int rb = 0;
  while (rem >= NTB - rb) { rem -= NTB - rb; rb++; }
  const int cb = rb + rem;

  const int t = threadIdx.x;
  const int l = t & 63, w = t >> 6;
  const int wr = w >> 2, wc = w & 3;          // 2 x 4 wave grid

  f32x4 acc[8][4];
  const f32x4 zero4 = {0.f, 0.f, 0.f, 0.f};
#pragma unroll
  for (int m = 0; m < 8; m++)
#pragma unroll
    for (int n = 0; n < 4; n++) acc[m][n] = zero4;

  // staging addressing: per inst, one wave covers 8 rows x 128B (1 KB contiguous LDS)
  const int srow8 = w * 8 + (l >> 3);          // row within 64-row inst chunk
  const int schunk = (l & 7) ^ (l >> 3);       // pre-swizzled source 16B chunk
  const size_t arow0 = (size_t)rb * 256;
  const size_t brow0 = (size_t)cb * 256;

  // read-side addressing (XOR swizzle matches pre-swizzled staging)
  const int swz = (l & 7) << 4;
  const int q16 = ((l >> 4) & 3) * 16;
  const int arow = wr * 128 + (l & 15);
  const int brow = wc * 64 + (l & 15);
  const int offk0 = (q16) ^ swz;
  const int offk1 = (64 + q16) ^ swz;

  // ---- prologue: B(0), A(0), B(1); wait first 8; preload regs for tile 0 ph1 ----
  SG_B(0, 0, lB0); SG_B(1, 0, lB0); SG_B(2, 0, lB0); SG_B(3, 0, lB0);
  SG_A(0, 0, lA0); SG_A(1, 0, lA0); SG_A(2, 0, lA0); SG_A(3, 0, lA0);
  SG_B(0, 1, lB1); SG_B(1, 1, lB1); SG_B(2, 1, lB1); SG_B(3, 1, lB1);
  WAITV(4);
  BARRIER();

  bf16x8 af[2][2], bfr[4][2];
  READ_AQ((const char*)lA0, 0);
  READ_B2((const char*)lB0, 0);
  READ_B2((const char*)lB0, 1);

#pragma unroll 1
  for (int kt = 0; kt < 14; ++kt) DO_TILE(kt, 1, 1, 1, 1, 4)
  DO_TILE(14, 1, 0, 1, 1, 0)
  DO_TILE(15, 0, 0, 0, 0, 0)

  // -------- epilogue: exp + diagonal mask + row/col partial sums --------
  float rsum[8][4];
  float csum[4];
#pragma unroll
  for (int m = 0; m < 8; m++)
#pragma unroll
    for (int j = 0; j < 4; j++) rsum[m][j] = 0.f;
#pragma unroll
  for (int n = 0; n < 4; n++) csum[n] = 0.f;

  const int col16 = l & 15, rgp = (l >> 4) & 3;
  const bool diag = (rb == cb);
  const int growbase = wr * 128 + rgp * 4;     // + m*16 + j  (within tile)
  const int gcolbase = wc * 64 + col16;        // + n*16      (within tile)
#pragma unroll
  for (int m = 0; m < 8; m++) {
#pragma unroll
    for (int n = 0; n < 4; n++) {
#pragma unroll
      for (int j = 0; j < 4; j++) {
        const float e = (diag && (growbase + m * 16 + j) == (gcolbase + n * 16))
                            ? 0.f
                            : exp2f(acc[m][n][j] * EXPSCALE);
        rsum[m][j] += e;
        csum[n] += e;
      }
    }
  }
#pragma unroll
  for (int m = 0; m < 8; m++)
#pragma unroll
    for (int j = 0; j < 4; j++) {
      float v = rsum[m][j];
      v += __shfl_xor(v, 1); v += __shfl_xor(v, 2);
      v += __shfl_xor(v, 4); v += __shfl_xor(v, 8);
      rsum[m][j] = v;
    }
#pragma unroll
  for (int n = 0; n < 4; n++) {
    float v = csum[n];
    v += __shfl_xor(v, 16); v += __shfl_xor(v, 32);
    csum[n] = v;
  }

  float* rS = (float*)smem;            // [4 wc][256 rows]
  float* cS = ((float*)smem) + 1024;   // [2 wr][256 cols]
  if (col16 == 0) {
#pragma unroll
    for (int m = 0; m < 8; m++)
#pragma unroll
      for (int j = 0; j < 4; j++)
        rS[wc * 256 + wr * 128 + m * 16 + rgp * 4 + j] = rsum[m][j];
  }
  if (rgp == 0) {
#pragma unroll
    for (int n = 0; n < 4; n++)
      cS[wr * 256 + wc * 64 + n * 16 + col16] = csum[n];
  }
  __syncthreads();
  if (t < 256) {
    const float rs = rS[t] + rS[256 + t] + rS[512 + t] + rS[768 + t];
    partial[(size_t)cb * N2 + rb * 256 + t] = rs;
    if (!diag) {
      const float cs = cS[t] + cS[256 + t];
      partial[(size_t)rb * N2 + cb * 256 + t] = cs;
    }
  }
}

// ---------------- Kernel C1: per-row denom = sum of 32 partials; log; block sum -----------
__device__ inline float blockReduce(float v, float* sred) {
#pragma unroll
  for (int o = 32; o > 0; o >>= 1) v += __shfl_xor(v, o);
  const int lane = threadIdx.x & 63, wid = threadIdx.x >> 6;
  if (lane == 0) sred[wid] = v;
  __syncthreads();
  v = sred[0] + sred[1] + sred[2] + sred[3];
  __syncthreads();
  return v;
}

__global__ __launch_bounds__(256) void kred1(const float* __restrict__ partial,
                                             float* __restrict__ bsum) {
  const int r = blockIdx.x * 256 + threadIdx.x;
  float d = 0.f;
#pragma unroll 8
  for (int cbx = 0; cbx < 32; ++cbx) d += partial[(size_t)cbx * N2 + r];
  float v = logf(d);
  __shared__ float sred[4];
  v = blockReduce(v, sred);
  if (threadIdx.x == 0) bsum[blockIdx.x] = v;
}

// ---------------- Kernel C2: final scalar -------------------------------------------------
__global__ __launch_bounds__(256) void kred2(const float* __restrict__ bsum,
                                             const float* __restrict__ pos,
                                             float* __restrict__ out) {
  const int t = threadIdx.x;
  float v = (t < 32) ? bsum[t] : 0.f;
  float p = 0.f;
  for (int k = t; k < BSZ; k += 256) p += pos[k];
  __shared__ float sred[4];
  v = blockReduce(v, sred);
  p = blockReduce(p, sred);
  if (t == 0) out[0] = (v - 2.0f * p / TEMPV) / (float)N2;
}

extern "C" void kernel_launch(void* const* d_in, const int* in_sizes, int n_in,
                              void* d_out, int out_size, void* d_ws, size_t ws_size,
                              hipStream_t stream) {
  const float* ei = (const float*)d_in[0];
  const float* ej = (const float*)d_in[1];
  char* ws = (char*)d_ws;
  unsigned short* reps = (unsigned short*)ws;                       // 16 MB bf16 [8192][1024]
  float* partial = (float*)(ws + (size_t)16 * 1024 * 1024);         // 1 MB  [32][8192]
  float* pos = (float*)(ws + (size_t)18 * 1024 * 1024);             // 16 KB [4096]
  float* bsum = (float*)(ws + (size_t)18 * 1024 * 1024 + 16384);    // 128 B [32]

  (void)hipFuncSetAttribute((const void*)kgemm3,
                            hipFuncAttributeMaxDynamicSharedMemorySize, 131072);

  knorm<<<BSZ, 256, 0, stream>>>(ei, ej, reps, pos);
  kgemm3<<<NBLK, 512, 131072, stream>>>((const short*)reps, partial);
  kred1<<<32, 256, 0, stream>>>(partial, bsum);
  kred2<<<1, 256, 0, stream>>>(bsum, pos, (float*)d_out);
}

// Round 5
// 100.476 us; speedup vs baseline: 1.3193x; 1.1259x over previous
//
#include <hip/hip_runtime.h>

#define BSZ 4096
#define D 1024
#define N2 8192
#define TEMPV 0.5f
// exp(x/T) = exp2(x * log2(e)/T)
#define EXPSCALE 2.8853900817779268f
#define NTB 32      // 8192 / 256 tiles per dim

typedef __attribute__((ext_vector_type(8))) short bf16x8;
typedef __attribute__((ext_vector_type(4))) float f32x4;

__device__ inline unsigned short f2bf(float x) {
  unsigned int u = __float_as_uint(x);
  u += 0x7fffu + ((u >> 16) & 1u);   // round-to-nearest-even
  return (unsigned short)(u >> 16);
}

__device__ inline void gload16(const void* g, void* l) {
  __builtin_amdgcn_global_load_lds(
      (const __attribute__((address_space(1))) void*)g,
      (__attribute__((address_space(3))) void*)l, 16, 0, 0);
}

// ---------------- Kernel A: L2-normalize rows, emit bf16 reps + pos dot ----------------
__global__ __launch_bounds__(256) void knorm(const float* __restrict__ ei,
                                             const float* __restrict__ ej,
                                             unsigned short* __restrict__ reps,
                                             float* __restrict__ pos) {
  const int r = blockIdx.x;
  const int t = threadIdx.x;
  const float4 vi = ((const float4*)(ei + (size_t)r * D))[t];
  const float4 vj = ((const float4*)(ej + (size_t)r * D))[t];
  float ssi = vi.x * vi.x + vi.y * vi.y + vi.z * vi.z + vi.w * vi.w;
  float ssj = vj.x * vj.x + vj.y * vj.y + vj.z * vj.z + vj.w * vj.w;
  float sij = vi.x * vj.x + vi.y * vj.y + vi.z * vj.z + vi.w * vj.w;
#pragma unroll
  for (int o = 32; o > 0; o >>= 1) {
    ssi += __shfl_xor(ssi, o);
    ssj += __shfl_xor(ssj, o);
    sij += __shfl_xor(sij, o);
  }
  __shared__ float red[12];
  const int lane = t & 63, wid = t >> 6;
  if (lane == 0) { red[wid * 3] = ssi; red[wid * 3 + 1] = ssj; red[wid * 3 + 2] = sij; }
  __syncthreads();
  ssi = red[0] + red[3] + red[6] + red[9];
  ssj = red[1] + red[4] + red[7] + red[10];
  sij = red[2] + red[5] + red[8] + red[11];
  const float inv_i = rsqrtf(fmaxf(ssi, 1e-24f));
  const float inv_j = rsqrtf(fmaxf(ssj, 1e-24f));
  ushort4 ui, uj;
  ui.x = f2bf(vi.x * inv_i); ui.y = f2bf(vi.y * inv_i);
  ui.z = f2bf(vi.z * inv_i); ui.w = f2bf(vi.w * inv_i);
  uj.x = f2bf(vj.x * inv_j); uj.y = f2bf(vj.y * inv_j);
  uj.z = f2bf(vj.z * inv_j); uj.w = f2bf(vj.w * inv_j);
  *((ushort4*)(reps + (size_t)r * D) + t) = ui;
  *((ushort4*)(reps + (size_t)(BSZ + r) * D) + t) = uj;
  if (t == 0) pos[r] = sij * inv_i * inv_j;
}

// ======================= shared asm helpers =======================
#define BARRIER() do { __builtin_amdgcn_s_barrier(); asm volatile("" ::: "memory"); } while (0)
#define STR2(x) #x
#define WAITV(n) asm volatile("s_waitcnt vmcnt(" STR2(n) ")" ::: "memory")

// ---------------- Kernel B: 256x256 tiles (512 of them = 2 clean rounds) ----------------
// 8 waves (2M x 4N), wave tile 128x64, BK=64, 128 KiB LDS (A dbuf + B dbuf).
#define SG_A(ii, ktv, dst) gload16(reps + (arow0 + (ii) * 64 + srow8) * D + (ktv) * 64 + schunk * 8, \
                                   (dst) + (size_t)((ii) * 64 + w * 8) * 64)
#define SG_B(ii, ktv, dst) gload16(reps + (brow0 + (ii) * 64 + srow8) * D + (ktv) * 64 + schunk * 8, \
                                   (dst) + (size_t)((ii) * 64 + w * 8) * 64)

#define READ_AQ(buf, q) do {                                            \
    const char* rp0_ = (buf) + (arow + (2 * (q)) * 16) * 128;           \
    const char* rp1_ = (buf) + (arow + (2 * (q) + 1) * 16) * 128;       \
    af[0][0] = *(const bf16x8*)(rp0_ + offk0);                          \
    af[0][1] = *(const bf16x8*)(rp0_ + offk1);                          \
    af[1][0] = *(const bf16x8*)(rp1_ + offk0);                          \
    af[1][1] = *(const bf16x8*)(rp1_ + offk1);                          \
  } while (0)

#define READ_B2(buf, n) do {                                            \
    const char* rp_ = (buf) + (brow + (n) * 16) * 128;                  \
    bfr[n][0] = *(const bf16x8*)(rp_ + offk0);                          \
    bfr[n][1] = *(const bf16x8*)(rp_ + offk1);                          \
  } while (0)

#define MFMA_Q(q)                                                       \
  __builtin_amdgcn_s_setprio(1);                                        \
  _Pragma("unroll") for (int nh = 0; nh < 2; nh++)                      \
  _Pragma("unroll") for (int kk = 0; kk < 2; kk++)                      \
  _Pragma("unroll") for (int m2 = 0; m2 < 2; m2++)                      \
  _Pragma("unroll") for (int nn = 0; nn < 2; nn++) {                    \
    const int n_ = nh * 2 + nn;                                         \
    acc[2 * (q) + m2][n_] = __builtin_amdgcn_mfma_f32_16x16x32_bf16(    \
        af[m2][kk], bfr[n_][kk], acc[2 * (q) + m2][n_], 0, 0, 0);       \
  }                                                                     \
  __builtin_amdgcn_s_setprio(0);

#define DO_TILE(ktv, SA, SB, RDN, HASW, WV)                             \
  {                                                                     \
    const int cur = (ktv) & 1;                                          \
    const char* bA  = cur ? (const char*)lA1 : (const char*)lA0;        \
    const char* bB  = cur ? (const char*)lB1 : (const char*)lB0;        \
    const char* bAn = cur ? (const char*)lA0 : (const char*)lA1;        \
    const char* bBn = cur ? (const char*)lB0 : (const char*)lB1;        \
    short* stA = cur ? lA0 : lA1;                                       \
    short* stB = cur ? lB1 : lB0;                                       \
    READ_B2(bB, 2); READ_B2(bB, 3);                                     \
    MFMA_Q(0);                                                          \
    READ_AQ(bA, 1);                                                     \
    if (SA) { SG_A(0, (ktv) + 1, stA); SG_A(1, (ktv) + 1, stA);         \
              SG_A(2, (ktv) + 1, stA); SG_A(3, (ktv) + 1, stA); }       \
    BARRIER();                                                          \
    MFMA_Q(1);                                                          \
    READ_AQ(bA, 2);                                                     \
    BARRIER();                                                          \
    MFMA_Q(2);                                                          \
    READ_AQ(bA, 3);                                                     \
    if (SB) { SG_B(0, (ktv) + 2, stB); SG_B(1, (ktv) + 2, stB);         \
              SG_B(2, (ktv) + 2, stB); SG_B(3, (ktv) + 2, stB); }       \
    if (HASW) { WAITV(WV); }                                            \
    BARRIER();                                                          \
    MFMA_Q(3);                                                          \
    if (RDN) { READ_AQ(bAn, 0); READ_B2(bBn, 0); READ_B2(bBn, 1); }     \
    BARRIER();                                                          \
  }

__global__ __launch_bounds__(512, 2) void kgemm3(const short* __restrict__ reps,
                                                 float* __restrict__ partial) {
  extern __shared__ char smem[];
  short* lA0 = (short*)smem;                  // 32 KB  [256][64]
  short* lA1 = (short*)(smem + 32768);
  short* lB0 = (short*)(smem + 65536);
  short* lB1 = (short*)(smem + 98304);

  // XCD-aware swizzle (512 = 8 * 64, bijective), then decode into the
  // 512-tile list: triangle minus tiles (0, 16..31).
  int bid = (int)blockIdx.x;
  bid = (bid & 7) * 64 + (bid >> 3);
  int rb, cb;
  if (bid < 16) {
    rb = 0; cb = bid;
  } else {
    int rem = bid - 16;
    rb = 1;
    while (rem >= NTB - rb) { rem -= NTB - rb; rb++; }
    cb = rb + rem;
  }

  const int t = threadIdx.x;
  const int l = t & 63, w = t >> 6;
  const int wr = w >> 2, wc = w & 3;          // 2 x 4 wave grid

  f32x4 acc[8][4];
  const f32x4 zero4 = {0.f, 0.f, 0.f, 0.f};
#pragma unroll
  for (int m = 0; m < 8; m++)
#pragma unroll
    for (int n = 0; n < 4; n++) acc[m][n] = zero4;

  const int srow8 = w * 8 + (l >> 3);          // row within 64-row inst chunk
  const int schunk = (l & 7) ^ (l >> 3);       // pre-swizzled source 16B chunk
  const size_t arow0 = (size_t)rb * 256;
  const size_t brow0 = (size_t)cb * 256;

  const int swz = (l & 7) << 4;
  const int q16 = ((l >> 4) & 3) * 16;
  const int arow = wr * 128 + (l & 15);
  const int brow = wc * 64 + (l & 15);
  const int offk0 = (q16) ^ swz;
  const int offk1 = (64 + q16) ^ swz;

  // ---- prologue ----
  SG_B(0, 0, lB0); SG_B(1, 0, lB0); SG_B(2, 0, lB0); SG_B(3, 0, lB0);
  SG_A(0, 0, lA0); SG_A(1, 0, lA0); SG_A(2, 0, lA0); SG_A(3, 0, lA0);
  SG_B(0, 1, lB1); SG_B(1, 1, lB1); SG_B(2, 1, lB1); SG_B(3, 1, lB1);
  WAITV(4);
  BARRIER();

  bf16x8 af[2][2], bfr[4][2];
  READ_AQ((const char*)lA0, 0);
  READ_B2((const char*)lB0, 0);
  READ_B2((const char*)lB0, 1);

#pragma unroll 1
  for (int kt = 0; kt < 14; ++kt) DO_TILE(kt, 1, 1, 1, 1, 4)
  DO_TILE(14, 1, 0, 1, 1, 0)
  DO_TILE(15, 0, 0, 0, 0, 0)

  // -------- epilogue: exp + diagonal mask + row/col partial sums --------
  float rsum[8][4];
  float csum[4];
#pragma unroll
  for (int m = 0; m < 8; m++)
#pragma unroll
    for (int j = 0; j < 4; j++) rsum[m][j] = 0.f;
#pragma unroll
  for (int n = 0; n < 4; n++) csum[n] = 0.f;

  const int col16 = l & 15, rgp = (l >> 4) & 3;
  const bool diag = (rb == cb);
  const int growbase = wr * 128 + rgp * 4;
  const int gcolbase = wc * 64 + col16;
#pragma unroll
  for (int m = 0; m < 8; m++) {
#pragma unroll
    for (int n = 0; n < 4; n++) {
#pragma unroll
      for (int j = 0; j < 4; j++) {
        const float e = (diag && (growbase + m * 16 + j) == (gcolbase + n * 16))
                            ? 0.f
                            : exp2f(acc[m][n][j] * EXPSCALE);
        rsum[m][j] += e;
        csum[n] += e;
      }
    }
  }
#pragma unroll
  for (int m = 0; m < 8; m++)
#pragma unroll
    for (int j = 0; j < 4; j++) {
      float v = rsum[m][j];
      v += __shfl_xor(v, 1); v += __shfl_xor(v, 2);
      v += __shfl_xor(v, 4); v += __shfl_xor(v, 8);
      rsum[m][j] = v;
    }
#pragma unroll
  for (int n = 0; n < 4; n++) {
    float v = csum[n];
    v += __shfl_xor(v, 16); v += __shfl_xor(v, 32);
    csum[n] = v;
  }

  float* rS = (float*)smem;            // [4 wc][256 rows]
  float* cS = ((float*)smem) + 1024;   // [2 wr][256 cols]
  if (col16 == 0) {
#pragma unroll
    for (int m = 0; m < 8; m++)
#pragma unroll
      for (int j = 0; j < 4; j++)
        rS[wc * 256 + wr * 128 + m * 16 + rgp * 4 + j] = rsum[m][j];
  }
  if (rgp == 0) {
#pragma unroll
    for (int n = 0; n < 4; n++)
      cS[wr * 256 + wc * 64 + n * 16 + col16] = csum[n];
  }
  __syncthreads();
  // partial layout: [64 col-blocks of 128][8192 rows]
  if (t < 256) {
    const float rs_lo = rS[t] + rS[256 + t];
    const float rs_hi = rS[512 + t] + rS[768 + t];
    partial[(size_t)(cb * 2) * N2 + rb * 256 + t] = rs_lo;
    partial[(size_t)(cb * 2 + 1) * N2 + rb * 256 + t] = rs_hi;
    if (!diag) {
      partial[(size_t)(rb * 2) * N2 + cb * 256 + t] = cS[t];
      partial[(size_t)(rb * 2 + 1) * N2 + cb * 256 + t] = cS[256 + t];
    }
  }
}

// ---------------- Kernel Bq: tail — 64 quarter-tiles (128x128) of tiles (0,16..31) ------
// 8 waves (2M x 4N), wave tile 64x32, BKQ=128, 8 K-iters, 2 barriers/iter,
// 2-tile-deep staging ledger (4 A + 4 B gloads per thread per tile), vmcnt(8).
#define QSG_A(ii, ktv, dst) gload16(reps + (qarow0 + (ii) * 32 + qsrow) * D + (ktv) * 128 + qschk * 8, \
                                    (dst) + (size_t)((ii) * 32 + w * 4) * 128)
#define QSG_B(ii, ktv, dst) gload16(reps + (qbrow0 + (ii) * 32 + qsrow) * D + (ktv) * 128 + qschk * 8, \
                                    (dst) + (size_t)((ii) * 32 + w * 4) * 128)

#define QRD(buf, row, kk) (*(const bf16x8*)((const char*)(buf) + (row) * 256 + \
                           ((((kk) * 4 + q4) ^ ((row) & 15)) << 4)))

#define QMFMA(afx, mb)                                                  \
  __builtin_amdgcn_s_setprio(1);                                        \
  _Pragma("unroll") for (int kk = 0; kk < 4; kk++)                      \
  _Pragma("unroll") for (int m2 = 0; m2 < 2; m2++)                      \
  _Pragma("unroll") for (int n = 0; n < 2; n++)                         \
    acc[(mb) + m2][n] = __builtin_amdgcn_mfma_f32_16x16x32_bf16(        \
        afx[m2][kk], bfr[n][kk], acc[(mb) + m2][n], 0, 0, 0);           \
  __builtin_amdgcn_s_setprio(0);

#define QTILE(tv, S, R, HASW, WV)                                       \
  {                                                                     \
    const int cur = (tv) & 1;                                           \
    const char* bA  = cur ? (const char*)qA1 : (const char*)qA0;        \
    const char* bAn = cur ? (const char*)qA0 : (const char*)qA1;        \
    const char* bBn = cur ? (const char*)qB0 : (const char*)qB1;        \
    short* stA = cur ? qA0 : qA1;                                       \
    short* stB = cur ? qB0 : qB1;                                       \
    /* ph1: read af23(t); MFMA m01 */                                   \
    _Pragma("unroll") for (int m2 = 0; m2 < 2; m2++)                    \
      _Pragma("unroll") for (int kk = 0; kk < 4; kk++)                  \
        af23[m2][kk] = QRD(bA, qarow + (2 + m2) * 16, kk);              \
    QMFMA(af01, 0);                                                     \
    BARRIER();                                                          \
    /* ph2: stage t+2; MFMA m23; counted wait; read t+1 operands */     \
    if (S) { QSG_A(0, (tv) + 2, stA); QSG_A(1, (tv) + 2, stA);          \
             QSG_A(2, (tv) + 2, stA); QSG_A(3, (tv) + 2, stA); }        \
    QMFMA(af23, 2);                                                     \
    if (S) { QSG_B(0, (tv) + 2, stB); QSG_B(1, (tv) + 2, stB);          \
             QSG_B(2, (tv) + 2, stB); QSG_B(3, (tv) + 2, stB); }        \
    if (HASW) { WAITV(WV); }                                            \
    BARRIER();                                                          \
    if (R) {                                                            \
      _Pragma("unroll") for (int m2 = 0; m2 < 2; m2++)                  \
        _Pragma("unroll") for (int kk = 0; kk < 4; kk++)                \
          af01[m2][kk] = QRD(bAn, qarow + m2 * 16, kk);                 \
      _Pragma("unroll") for (int n = 0; n < 2; n++)                     \
        _Pragma("unroll") for (int kk = 0; kk < 4; kk++)                \
          bfr[n][kk] = QRD(bBn, qbrow + n * 16, kk);                    \
    }                                                                   \
  }

__global__ __launch_bounds__(512) void kgemmq(const short* __restrict__ reps,
                                              float* __restrict__ partial) {
  extern __shared__ char smem[];
  short* qA0 = (short*)smem;                  // 32 KB [128][128]
  short* qA1 = (short*)(smem + 32768);
  short* qB0 = (short*)(smem + 65536);
  short* qB1 = (short*)(smem + 98304);

  const int bq = (int)blockIdx.x;             // 0..63
  const int s = bq >> 2, quad = bq & 3;
  const int qr = quad >> 1, qc = quad & 1;
  const int cbt = 16 + s;

  const int t = threadIdx.x;
  const int l = t & 63, w = t >> 6;
  const int wr = w >> 2, wc = w & 3;

  f32x4 acc[4][2];
  const f32x4 zero4 = {0.f, 0.f, 0.f, 0.f};
#pragma unroll
  for (int m = 0; m < 4; m++)
#pragma unroll
    for (int n = 0; n < 2; n++) acc[m][n] = zero4;

  // staging: inst = 512 lanes x 16B = 32 rows of 256B
  const int qsrow = w * 4 + (l >> 4);          // row within 32-row inst chunk
  const int qschk = (l & 15) ^ (qsrow & 15);   // pre-swizzled source chunk
  const size_t qarow0 = (size_t)qr * 128;
  const size_t qbrow0 = (size_t)cbt * 256 + (size_t)qc * 128;

  // read side
  const int q4 = (l >> 4) & 3;
  const int qarow = wr * 64 + (l & 15);
  const int qbrow = wc * 32 + (l & 15);

  // ---- prologue: tiles 0 and 1 staged; wait tile 0; preload operands ----
  QSG_A(0, 0, qA0); QSG_A(1, 0, qA0); QSG_A(2, 0, qA0); QSG_A(3, 0, qA0);
  QSG_B(0, 0, qB0); QSG_B(1, 0, qB0); QSG_B(2, 0, qB0); QSG_B(3, 0, qB0);
  QSG_A(0, 1, qA1); QSG_A(1, 1, qA1); QSG_A(2, 1, qA1); QSG_A(3, 1, qA1);
  QSG_B(0, 1, qB1); QSG_B(1, 1, qB1); QSG_B(2, 1, qB1); QSG_B(3, 1, qB1);
  WAITV(8);
  BARRIER();

  bf16x8 af01[2][4], af23[2][4], bfr[2][4];
#pragma unroll
  for (int m2 = 0; m2 < 2; m2++)
#pragma unroll
    for (int kk = 0; kk < 4; kk++)
      af01[m2][kk] = QRD((const char*)qA0, qarow + m2 * 16, kk);
#pragma unroll
  for (int n = 0; n < 2; n++)
#pragma unroll
    for (int kk = 0; kk < 4; kk++)
      bfr[n][kk] = QRD((const char*)qB0, qbrow + n * 16, kk);

#pragma unroll 1
  for (int tv = 0; tv < 6; ++tv) QTILE(tv, 1, 1, 1, 8)
  QTILE(6, 0, 1, 1, 0)
  QTILE(7, 0, 0, 0, 0)

  // -------- epilogue (no diagonal possible: rows < 256, cols >= 4096) --------
  float rsum[4][4];
  float csum[2];
#pragma unroll
  for (int m = 0; m < 4; m++)
#pragma unroll
    for (int j = 0; j < 4; j++) rsum[m][j] = 0.f;
  csum[0] = 0.f; csum[1] = 0.f;

#pragma unroll
  for (int m = 0; m < 4; m++)
#pragma unroll
    for (int n = 0; n < 2; n++)
#pragma unroll
      for (int j = 0; j < 4; j++) {
        const float e = exp2f(acc[m][n][j] * EXPSCALE);
        rsum[m][j] += e;
        csum[n] += e;
      }
#pragma unroll
  for (int m = 0; m < 4; m++)
#pragma unroll
    for (int j = 0; j < 4; j++) {
      float v = rsum[m][j];
      v += __shfl_xor(v, 1); v += __shfl_xor(v, 2);
      v += __shfl_xor(v, 4); v += __shfl_xor(v, 8);
      rsum[m][j] = v;
    }
#pragma unroll
  for (int n = 0; n < 2; n++) {
    float v = csum[n];
    v += __shfl_xor(v, 16); v += __shfl_xor(v, 32);
    csum[n] = v;
  }

  const int col16 = l & 15, rgp = (l >> 4) & 3;
  float* rS = (float*)smem;            // [4 wc][128 rows]
  float* cS = ((float*)smem) + 512;    // [2 wr][128 cols]
  if (col16 == 0) {
#pragma unroll
    for (int m = 0; m < 4; m++)
#pragma unroll
      for (int j = 0; j < 4; j++)
        rS[wc * 128 + wr * 64 + m * 16 + rgp * 4 + j] = rsum[m][j];
  }
  if (rgp == 0) {
#pragma unroll
    for (int n = 0; n < 2; n++)
      cS[wr * 128 + wc * 32 + n * 16 + col16] = csum[n];
  }
  __syncthreads();
  if (t < 128) {
    const float rs = rS[t] + rS[128 + t] + rS[256 + t] + rS[384 + t];
    partial[(size_t)(cbt * 2 + qc) * N2 + qr * 128 + t] = rs;
    const float cs = cS[t] + cS[128 + t];
    partial[(size_t)qr * N2 + cbt * 256 + qc * 128 + t] = cs;
  }
}

// ---------------- Kernel C1: per-row denom = sum of 64 partials; log; block sum -----------
__device__ inline float blockReduce(float v, float* sred) {
#pragma unroll
  for (int o = 32; o > 0; o >>= 1) v += __shfl_xor(v, o);
  const int lane = threadIdx.x & 63, wid = threadIdx.x >> 6;
  if (lane == 0) sred[wid] = v;
  __syncthreads();
  v = sred[0] + sred[1] + sred[2] + sred[3];
  __syncthreads();
  return v;
}

__global__ __launch_bounds__(256) void kred1(const float* __restrict__ partial,
                                             float* __restrict__ bsum) {
  const int r = blockIdx.x * 256 + threadIdx.x;
  float d = 0.f;
#pragma unroll 8
  for (int cbx = 0; cbx < 64; ++cbx) d += partial[(size_t)cbx * N2 + r];
  float v = logf(d);
  __shared__ float sred[4];
  v = blockReduce(v, sred);
  if (threadIdx.x == 0) bsum[blockIdx.x] = v;
}

// ---------------- Kernel C2: final scalar -------------------------------------------------
__global__ __launch_bounds__(256) void kred2(const float* __restrict__ bsum,
                                             const float* __restrict__ pos,
                                             float* __restrict__ out) {
  const int t = threadIdx.x;
  float v = (t < 32) ? bsum[t] : 0.f;
  float p = 0.f;
  for (int k = t; k < BSZ; k += 256) p += pos[k];
  __shared__ float sred[4];
  v = blockReduce(v, sred);
  p = blockReduce(p, sred);
  if (t == 0) out[0] = (v - 2.0f * p / TEMPV) / (float)N2;
}

extern "C" void kernel_launch(void* const* d_in, const int* in_sizes, int n_in,
                              void* d_out, int out_size, void* d_ws, size_t ws_size,
                              hipStream_t stream) {
  const float* ei = (const float*)d_in[0];
  const float* ej = (const float*)d_in[1];
  char* ws = (char*)d_ws;
  unsigned short* reps = (unsigned short*)ws;                       // 16 MB bf16 [8192][1024]
  float* partial = (float*)(ws + (size_t)16 * 1024 * 1024);         // 2 MB  [64][8192]
  float* pos = (float*)(ws + (size_t)18 * 1024 * 1024);             // 16 KB [4096]
  float* bsum = (float*)(ws + (size_t)18 * 1024 * 1024 + 16384);    // 128 B [32]

  (void)hipFuncSetAttribute((const void*)kgemm3,
                            hipFuncAttributeMaxDynamicSharedMemorySize, 131072);
  (void)hipFuncSetAttribute((const void*)kgemmq,
                            hipFuncAttributeMaxDynamicSharedMemorySize, 131072);

  knorm<<<BSZ, 256, 0, stream>>>(ei, ej, reps, pos);
  kgemm3<<<512, 512, 131072, stream>>>((const short*)reps, partial);
  kgemmq<<<64, 512, 131072, stream>>>((const short*)reps, partial);
  kred1<<<32, 256, 0, stream>>>(partial, bsum);
  kred2<<<1, 256, 0, stream>>>(bsum, pos, (float*)d_out);
}